// Round 12
// baseline (149.694 us; speedup 1.0000x reference)
//
#include <hip/hip_runtime.h>

// Causal flash attention, B=4 L=S=2048 H=8 E=D=64, fp32 in/out, bf16 MFMA.
// Round 19 = round 18 resubmit (infra "container failed twice", same signature
// as the round-4 flake; design audit found no deadlock/crash path) with one
// hardening: kfr/vfr init is UNCONDITIONAL (clamped tile min(w,T-1)) to remove
// the formally-uninitialized-read corner for idle waves.
// Design (unbenched, from R17's validated 49.3us engine):
//  (1) Register double-prefetch: K(kt+4)/V(kt+4) loaded into the SAME
//      kfr/vfr regs right after their last use, pinned by
//      sched_barrier(0x38F) (ALU|VALU|SALU|MFMA|DS may cross, VMEM may NOT)
//      so the compiler cannot sink the loads to their use sites (R17
//      VGPR=76 proved it does by default -> serial L2 round-trips per tile).
//  (2) LB(256,2): reg cap 256 so the +64-reg prefetch set cannot spill.
//  (3) Round-robin split-K (kt = w, w+4, ...): chain lengths differ by <=1.
//  (4) max3-shaped max reduction.
// Everything else verbatim from R17: 4-wave blocks on one 32-row strip,
// frag-major bf16 workspace loads, swapped QK^T, in-lane softmax,
// pack2+permlane32_swap P-frags, defer-max THR=8, exact LDS merge tree.

typedef unsigned short u16;
typedef unsigned int   u32;
typedef short short8   __attribute__((ext_vector_type(8)));
typedef float floatx16 __attribute__((ext_vector_type(16)));
typedef u32 u32x4      __attribute__((ext_vector_type(4)));

#define B_ 4
#define L_ 2048
#define S_ 2048
#define H_ 8
#define E_ 64
#define D_ 64

// round-half-up fp32->bf16 pair, lo in low 16 bits
static __device__ __forceinline__ u32 pack2(float lo, float hi) {
    const u32 a = __float_as_uint(lo) + 0x8000u;
    const u32 b = __float_as_uint(hi) + 0x8000u;
    return __builtin_amdgcn_perm(b, a, 0x07060302u);
}
static __device__ __forceinline__ u16 bf16c(float x) {
    return (u16)((__float_as_uint(x) + 0x8000u) >> 16);
}
// v_permlane32_swap_b32: a.hi32lanes <-> b.lo32lanes
static __device__ __forceinline__ void pl32swap(u32& a, u32& b) {
    asm("v_permlane32_swap_b32 %0, %1" : "+v"(a), "+v"(b));
}
static __device__ __forceinline__ floatx16 zero16() {
    floatx16 z;
    #pragma unroll
    for (int i = 0; i < 16; i++) z[i] = 0.f;
    return z;
}

// ---------------- pre-pass: fp32 -> bf16, FRAG-MAJOR tiles ----------------
// Kc tile (per bh,kt; 4096 u16): [F=mt*4+ks][lane=hi*32+l31][j]
//   holds K[b][s=kt*64+mt*32+l31][h][e=ks*16+hi*8+j]
// Vt tile (per bh,kt; 4096 u16): [F=nt*4+ks][lane=hi*32+l31][j]
//   holds V[b][s=kt*64+ks*16+hi*8+j][h][d=nt*32+l31]
__global__ __launch_bounds__(256)
void cvt_kernel(const float* __restrict__ k, const float* __restrict__ v,
                u16* __restrict__ kc, u16* __restrict__ vt)
{
    __shared__ u16 Lt[64 * 72];
    const int bx = blockIdx.x, t = threadIdx.x;
    const int tile = bx & 1023;
    const int kt = tile & 31, h = (tile >> 5) & 7, b = tile >> 8;
    const int F  = t >> 5;
    const int hi = (t >> 4) & 1;
    const int l0 = (t & 15) * 2;

    if (bx < 1024) {
        const int mt = F >> 2, ks = F & 3;
        const int s  = kt * 64 + mt * 32 + l0;
        const int e  = ks * 16 + hi * 8;
        const float* p0 = k + (((size_t)(b * S_ + s)) * H_ + h) * E_ + e;
        const float4 a0 = ((const float4*)p0)[0], a1 = ((const float4*)p0)[1];
        const float* p1 = p0 + H_ * E_;
        const float4 b0 = ((const float4*)p1)[0], b1 = ((const float4*)p1)[1];
        u16* dst = kc + ((size_t)(b * 8 + h)) * 131072 + (size_t)kt * 4096 + t * 16;
        *(u32x4*)dst = (u32x4){pack2(a0.x, a0.y), pack2(a0.z, a0.w),
                               pack2(a1.x, a1.y), pack2(a1.z, a1.w)};
        *(u32x4*)(dst + 8) = (u32x4){pack2(b0.x, b0.y), pack2(b0.z, b0.w),
                                     pack2(b1.x, b1.y), pack2(b1.z, b1.w)};
    } else {
        {
            const int i  = t >> 2;
            const int d0 = (t & 3) * 16;
            const float* vp = v + (((size_t)(b * S_ + kt * 64 + i)) * H_ + h) * D_ + d0;
            const float4 a0 = ((const float4*)vp)[0], a1 = ((const float4*)vp)[1];
            const float4 a2 = ((const float4*)vp)[2], a3 = ((const float4*)vp)[3];
            const float va[16] = {a0.x,a0.y,a0.z,a0.w, a1.x,a1.y,a1.z,a1.w,
                                  a2.x,a2.y,a2.z,a2.w, a3.x,a3.y,a3.z,a3.w};
            #pragma unroll
            for (int jj = 0; jj < 16; jj++) Lt[(d0 + jj) * 72 + i] = bf16c(va[jj]);
        }
        __syncthreads();
        {
            const int nt = F >> 2, ks = F & 3;
            const int d1 = nt * 32 + l0;
            u16* dst = vt + ((size_t)(b * 8 + h)) * 131072 + (size_t)kt * 4096 + t * 16;
            *(u32x4*)dst       = *(const u32x4*)&Lt[(d1    ) * 72 + ks * 16 + hi * 8];
            *(u32x4*)(dst + 8) = *(const u32x4*)&Lt[(d1 + 1) * 72 + ks * 16 + hi * 8];
        }
    }
}

// ---------------- main kernel ----------------
// Grid 2048 x 256thr (4 waves). bx bits: [0:2]=h, [3:4]=b, [5:10]=ss.
// s = 63-ss (big strips first). Block covers strip rows q0=32s..32s+31;
// T = s/2+1 k-tiles distributed ROUND-ROBIN: wave w takes kt = w, w+4, ...
// (chain lengths differ by <=1). Exact LDS merge tree at block end.
template<int SRC>
__global__ __launch_bounds__(256, 2)
void fa_kernel(const float* __restrict__ q, const float* __restrict__ kk,
               const float* __restrict__ vv, const u16* __restrict__ kc,
               const u16* __restrict__ vt, float* __restrict__ out)
{
    __shared__ float Ms[2][2176];   // [slot][(nt*16+r)*64+lane | 2048+m | 2112+l]

    const int tid  = threadIdx.x;
    const int w    = tid >> 6;
    const int lane = tid & 63;
    const int l31  = lane & 31;
    const int hi   = lane >> 5;

    const int bx   = blockIdx.x;
    const int h    = bx & 7;
    const int b    = (bx >> 3) & 3;
    const int ss   = bx >> 5;                 // 0..63
    const int s    = 63 - ss;                 // strip; big first
    const int T    = (s >> 1) + 1;            // k-tiles for this strip
    const int Tm1  = T - 1;
    const int q0   = 32 * s;

    const float kscale = 0.18033688011112042f; // (1/sqrt(64)) * log2(e)

    // ---- Q frags (B-operand of S^T = K*Q^T), kscale folded ----
    const float* qptr = q + (((size_t)b * L_ + q0 + l31) * H_ + h) * E_ + hi * 8;
    short8 qf[4];
    #pragma unroll
    for (int ks = 0; ks < 4; ks++) {
        const float4 a0 = *(const float4*)(qptr + ks * 16);
        const float4 a1 = *(const float4*)(qptr + ks * 16 + 4);
        const u32x4 u = {pack2(a0.x * kscale, a0.y * kscale), pack2(a0.z * kscale, a0.w * kscale),
                         pack2(a1.x * kscale, a1.y * kscale), pack2(a1.z * kscale, a1.w * kscale)};
        qf[ks] = __builtin_bit_cast(short8, u);
    }

    const size_t bh = (size_t)(b * 8 + h);
    const u16* kcb = kc + bh * 131072;
    const u16* vtb = vt + bh * 131072;

    auto loadK = [&](int kt, int mt, int ks) -> short8 {
        if constexpr (SRC == 0) {
            const u32x4 u = *(const u32x4*)&kcb[(size_t)kt * 4096 + (mt * 4 + ks) * 512 + lane * 8];
            return __builtin_bit_cast(short8, u);
        } else {
            const float* p = kk + (((size_t)b * S_ + kt * 64 + mt * 32 + l31) * H_ + h) * E_ + ks * 16 + hi * 8;
            const float4 a0 = *(const float4*)p;
            const float4 a1 = *(const float4*)(p + 4);
            const u32x4 u = {pack2(a0.x, a0.y), pack2(a0.z, a0.w), pack2(a1.x, a1.y), pack2(a1.z, a1.w)};
            return __builtin_bit_cast(short8, u);
        }
    };
    auto loadV = [&](int kt, int nt, int ks) -> short8 {
        if constexpr (SRC == 0) {
            const u32x4 u = *(const u32x4*)&vtb[(size_t)kt * 4096 + (nt * 4 + ks) * 512 + lane * 8];
            return __builtin_bit_cast(short8, u);
        } else {
            float f[8];
            #pragma unroll
            for (int jj = 0; jj < 8; jj++)
                f[jj] = vv[(((size_t)b * S_ + kt * 64 + ks * 16 + hi * 8 + jj) * H_ + h) * D_ + nt * 32 + l31];
            const u32x4 u = {pack2(f[0], f[1]), pack2(f[2], f[3]), pack2(f[4], f[5]), pack2(f[6], f[7])};
            return __builtin_bit_cast(short8, u);
        }
    };

    floatx16 occ[2] = {zero16(), zero16()};  // O^T: col = q = l31
    float m_run = -1e30f, l_run = 0.f;

    // prologue: first tile (clamped for idle waves -- no uninitialized reads)
    short8 kfr[2][4], vfr[2][4];
    {
        const int kp = (w < T) ? w : Tm1;
        #pragma unroll
        for (int mt = 0; mt < 2; mt++)
            #pragma unroll
            for (int ks = 0; ks < 4; ks++) {
                kfr[mt][ks] = loadK(kp, mt, ks);
                vfr[mt][ks] = loadV(kp, mt, ks);
            }
    }

    for (int kt = w; kt < T; kt += 4) {
        // ---- S^T = K*Q^T (kfr prefetched one iteration ago) ----
        floatx16 sac[2];
        __builtin_amdgcn_s_setprio(1);
        #pragma unroll
        for (int mt = 0; mt < 2; mt++) {
            floatx16 c = zero16();
            #pragma unroll
            for (int ks = 0; ks < 4; ks++)
                c = __builtin_amdgcn_mfma_f32_32x32x16_bf16(kfr[mt][ks], qf[ks], c, 0, 0, 0);
            sac[mt] = c;
        }
        __builtin_amdgcn_s_setprio(0);

        // ---- prefetch next K into the same regs (WAR-safe: QK issued) ----
        if (kt + 4 < T) {
            #pragma unroll
            for (int mt = 0; mt < 2; mt++)
                #pragma unroll
                for (int ks = 0; ks < 4; ks++) kfr[mt][ks] = loadK(kt + 4, mt, ks);
        }
        // VMEM may not cross; VALU/SALU/MFMA/DS may (T19 mask mechanism)
        __builtin_amdgcn_sched_barrier(0x38F);

        // ---- causal mask (diagonal tile only) ----
        if (kt == Tm1) {
            const int qg = q0 + l31;
            #pragma unroll
            for (int mt = 0; mt < 2; mt++)
                #pragma unroll
                for (int r = 0; r < 16; r++) {
                    const int keyg = kt * 64 + mt * 32 + (r & 3) + (r >> 2) * 8 + hi * 4;
                    if (keyg > qg) sac[mt][r] = -1e30f;
                }
        }

        // ---- online softmax, in-lane + 1 shfl; defer-max (THR=8) ----
        float m01[16];
        #pragma unroll
        for (int r = 0; r < 16; r++) m01[r] = fmaxf(sac[0][r], sac[1][r]);
        // max3-shaped 16->1 reduce (clang fuses fmaxf(fmaxf) -> v_max3_f32)
        const float a0 = fmaxf(fmaxf(m01[0],  m01[1]),  m01[2]);
        const float a1 = fmaxf(fmaxf(m01[3],  m01[4]),  m01[5]);
        const float a2 = fmaxf(fmaxf(m01[6],  m01[7]),  m01[8]);
        const float a3 = fmaxf(fmaxf(m01[9],  m01[10]), m01[11]);
        const float a4 = fmaxf(fmaxf(m01[12], m01[13]), m01[14]);
        const float b0 = fmaxf(fmaxf(a0, a1), m01[15]);
        const float b1 = fmaxf(fmaxf(a2, a3), a4);
        const float mxl = fmaxf(b0, b1);
        const float mx  = fmaxf(mxl, __shfl_xor(mxl, 32));

        const bool defer = __all(mx - m_run <= 8.0f) != 0;
        if (!defer) {
            const float mnew  = fmaxf(m_run, mx);
            const float alpha = exp2f(m_run - mnew);
            m_run = mnew;
            l_run *= alpha;
            #pragma unroll
            for (int r = 0; r < 16; r++) { occ[0][r] *= alpha; occ[1][r] *= alpha; }
        }

        float sum[16];
        #pragma unroll
        for (int r = 0; r < 16; r++) {
            sac[0][r] = exp2f(sac[0][r] - m_run);
            sac[1][r] = exp2f(sac[1][r] - m_run);
            sum[r] = sac[0][r] + sac[1][r];
        }
        #pragma unroll
        for (int stp = 8; stp > 0; stp >>= 1)
            #pragma unroll
            for (int r = 0; r < stp; r++) sum[r] += sum[r + stp];
        l_run += sum[0] + __shfl_xor(sum[0], 32);

        // ---- P -> bf16 pairs ----
        u32 pk0[8], pk1[8];
        #pragma unroll
        for (int r2 = 0; r2 < 4; r2++) {
            pk0[2 * r2 + 0] = pack2(sac[0][4 * r2 + 0], sac[0][4 * r2 + 1]);
            pk0[2 * r2 + 1] = pack2(sac[0][4 * r2 + 2], sac[0][4 * r2 + 3]);
            pk1[2 * r2 + 0] = pack2(sac[1][4 * r2 + 0], sac[1][4 * r2 + 1]);
            pk1[2 * r2 + 1] = pack2(sac[1][4 * r2 + 2], sac[1][4 * r2 + 3]);
        }

        // ---- O^T += V^T * P (permlane32_swap builds B-frags) ----
        __builtin_amdgcn_s_setprio(1);
        #pragma unroll
        for (int ks = 0; ks < 4; ks++) {
            const int u = (ks & 1) * 4;
            u32 w0, w1, w2, w3;
            if (ks < 2) { w0 = pk0[u]; w1 = pk0[u + 1]; w2 = pk0[u + 2]; w3 = pk0[u + 3]; }
            else        { w0 = pk1[u]; w1 = pk1[u + 1]; w2 = pk1[u + 2]; w3 = pk1[u + 3]; }
            pl32swap(w0, w2);
            pl32swap(w1, w3);
            const u32x4 pw = {w0, w1, w2, w3};
            const short8 pf = __builtin_bit_cast(short8, pw);
            occ[0] = __builtin_amdgcn_mfma_f32_32x32x16_bf16(vfr[0][ks], pf, occ[0], 0, 0, 0);
            occ[1] = __builtin_amdgcn_mfma_f32_32x32x16_bf16(vfr[1][ks], pf, occ[1], 0, 0, 0);
        }
        __builtin_amdgcn_s_setprio(0);

        // ---- prefetch next V into the same regs (WAR-safe: PV issued) ----
        if (kt + 4 < T) {
            #pragma unroll
            for (int nt = 0; nt < 2; nt++)
                #pragma unroll
                for (int ks = 0; ks < 4; ks++) vfr[nt][ks] = loadV(kt + 4, nt, ks);
        }
        __builtin_amdgcn_sched_barrier(0x38F);   // pin V issue before iter end
    }

    // ---- merge tree: (w1->w0), (w3->w2), then (w2->w0); exact math ----
    auto dump = [&](int slot) {
        #pragma unroll
        for (int nt = 0; nt < 2; nt++)
            #pragma unroll
            for (int r = 0; r < 16; r++) Ms[slot][(nt * 16 + r) * 64 + lane] = occ[nt][r];
        Ms[slot][2048 + lane] = m_run;
        Ms[slot][2112 + lane] = l_run;
    };
    auto mergeIn = [&](int slot) {
        const float mB = Ms[slot][2048 + lane], lB = Ms[slot][2112 + lane];
        const float m  = fmaxf(m_run, mB);
        const float aA = exp2f(m_run - m), aB = exp2f(mB - m);
        m_run = m;
        l_run = l_run * aA + lB * aB;
        #pragma unroll
        for (int nt = 0; nt < 2; nt++)
            #pragma unroll
            for (int r = 0; r < 16; r++)
                occ[nt][r] = occ[nt][r] * aA + Ms[slot][(nt * 16 + r) * 64 + lane] * aB;
    };

    __syncthreads();
    if (w == 1 || w == 3) dump(w >> 1);
    __syncthreads();
    if (w == 0 || w == 2) mergeIn(w >> 1);
    __syncthreads();
    if (w == 2) dump(1);
    __syncthreads();
    if (w == 0) {
        mergeIn(1);
        const float inv = 1.0f / l_run;
        float* op = out + (((size_t)b * L_ + q0 + l31) * H_ + h) * D_;
        #pragma unroll
        for (int nt = 0; nt < 2; nt++)
            #pragma unroll
            for (int r2 = 0; r2 < 4; r2++) {
                const float4 o = {occ[nt][4 * r2 + 0] * inv, occ[nt][4 * r2 + 1] * inv,
                                  occ[nt][4 * r2 + 2] * inv, occ[nt][4 * r2 + 3] * inv};
                *(float4*)(op + nt * 32 + r2 * 8 + hi * 4) = o;
            }
    }
}

extern "C" void kernel_launch(void* const* d_in, const int* in_sizes, int n_in,
                              void* d_out, int out_size, void* d_ws, size_t ws_size,
                              hipStream_t stream) {
    const float* q = (const float*)d_in[0];
    const float* k = (const float*)d_in[1];
    const float* v = (const float*)d_in[2];
    // d_in[3] = attn_mask: fixed causal triu -> handled analytically in-kernel.
    float* out = (float*)d_out;

    const size_t elems = (size_t)B_ * H_ * S_ * E_;   // per tensor (u16 count)
    const size_t need  = elems * 2 * 2;               // Kc + Vt, bf16
    if (d_ws != nullptr && ws_size >= need) {
        u16* kc = (u16*)d_ws;
        u16* vt = kc + elems;
        cvt_kernel<<<dim3(2048), dim3(256), 0, stream>>>(k, v, kc, vt);
        fa_kernel<0><<<dim3(2048), dim3(256), 0, stream>>>(q, k, v, kc, vt, out);
    } else {
        fa_kernel<1><<<dim3(2048), dim3(256), 0, stream>>>(q, k, v, nullptr, nullptr, out);
    }
}